// Round 20
// baseline (50.639 us; speedup 1.0000x reference)
//
#include <hip/hip_runtime.h>

constexpr float EPS_LN = 1e-5f;
constexpr size_t BUNDLE = 622592;  // shorts per weight-bundle copy (1.2MB)

using f32x4 = __attribute__((ext_vector_type(4))) float;
using s16x8 = __attribute__((ext_vector_type(8))) short;

__device__ __forceinline__ short f2bf(float f) {
  union { float f; unsigned u; } v; v.f = f;
  unsigned r = v.u + 0x7fff + ((v.u >> 16) & 1);
  return (short)(r >> 16);
}
__device__ __forceinline__ float bf2f(short h) {
  union { unsigned u; float f; } v;
  v.u = ((unsigned)(unsigned short)h) << 16;
  return v.f;
}

__device__ __forceinline__ s16x8 cvt8(float4 a, float4 b) {
  s16x8 r;
  r[0] = f2bf(a.x); r[1] = f2bf(a.y); r[2] = f2bf(a.z); r[3] = f2bf(a.w);
  r[4] = f2bf(b.x); r[5] = f2bf(b.y); r[6] = f2bf(b.z); r[7] = f2bf(b.w);
  return r;
}

#define MFMA(a, b, c) __builtin_amdgcn_mfma_f32_16x16x32_bf16((a), (b), (c), 0, 0, 0)

__device__ __forceinline__ void gld_lds16(const void* g, void* l) {
  __builtin_amdgcn_global_load_lds(
      (const __attribute__((address_space(1))) unsigned int*)g,
      (__attribute__((address_space(3))) unsigned int*)l, 16, 0, 0);
}

struct P {
  const int* uid;
  const float *qe, *le, *tab;
  const float *Wu0, *bu0, *Wq0, *bq0, *Wl0, *bl0, *g0, *be0;
  const float *Wu1, *bu1, *Wq1, *bq1, *Wl1, *bl1, *g1, *be1;
  const float *w1, *b1, *w2, *b2;
  short *wt0u, *wt0q, *wt0l, *wt1u, *wt1q, *wt1l, *w1tU, *w1tL;  // copy 0
  short *uqU, *uqQ;
  float *lw, *out;
};

// Direct global->VGPR B-fragment GEMM over the chunk-sequential swizzled
// weight layout (short idx = kk*8192 + (kg*256 + col)*8 + ko).
template<int NK>
__device__ __forceinline__ void dgemm(const short* __restrict__ wt,
                                      const s16x8* aF, int lg, int lr, int c0,
                                      f32x4 acc[4]) {
  #pragma unroll
  for (int kk = 0; kk < NK; ++kk) {
    const short* base = wt + (size_t)kk * 8192 + (size_t)(lg * 256 + c0 + lr) * 8;
    #pragma unroll
    for (int n = 0; n < 4; ++n) {
      const s16x8 bf = *(const s16x8*)(base + n * 128);
      acc[n] = MFMA(aF[kk], bf, acc[n]);
    }
  }
}

// LayerNorm over 256 cols; in-place on z[n][r] (col=c0+n*16+lr, row=lg*4+r).
__device__ __forceinline__ void ln16(float z[4][4], int tid, int w, int lr, int lg,
                                     int c0, const float* __restrict__ g,
                                     const float* __restrict__ be,
                                     float (*ssum)[16], float (*ssq)[16],
                                     float* mub, float* rsb) {
  __syncthreads();
  float s1[4] = {0, 0, 0, 0}, s2[4] = {0, 0, 0, 0};
  #pragma unroll
  for (int n = 0; n < 4; ++n)
    #pragma unroll
    for (int r = 0; r < 4; ++r) { s1[r] += z[n][r]; s2[r] += z[n][r] * z[n][r]; }
  #pragma unroll
  for (int off = 1; off < 16; off <<= 1)
    #pragma unroll
    for (int r = 0; r < 4; ++r) {
      s1[r] += __shfl_xor(s1[r], off, 64);
      s2[r] += __shfl_xor(s2[r], off, 64);
    }
  if (lr == 0) {
    #pragma unroll
    for (int r = 0; r < 4; ++r) { ssum[w][lg * 4 + r] = s1[r]; ssq[w][lg * 4 + r] = s2[r]; }
  }
  __syncthreads();
  if (tid < 16) {
    float S1 = 0, S2 = 0;
    #pragma unroll
    for (int ww = 0; ww < 4; ++ww) { S1 += ssum[ww][tid]; S2 += ssq[ww][tid]; }
    float mu = S1 * (1.f / 256.f);
    float var = S2 * (1.f / 256.f) - mu * mu;
    mub[tid] = mu;
    rsb[tid] = rsqrtf(var + EPS_LN);
  }
  __syncthreads();
  #pragma unroll
  for (int n = 0; n < 4; ++n) {
    const int c = c0 + n * 16 + lr;
    const float gv = g[c], bv = be[c];
    #pragma unroll
    for (int r = 0; r < 4; ++r) {
      const int rr = lg * 4 + r;
      z[n][r] = gv * (z[n][r] - mub[rr]) * rsb[rr] + bv;
    }
  }
}

__device__ __forceinline__ void bias2(const f32x4 acc[4], const float* __restrict__ b,
                                      int c0, int lr, float z[4][4]) {
  #pragma unroll
  for (int n = 0; n < 4; ++n) {
    const float bv = b[c0 + n * 16 + lr];
    #pragma unroll
    for (int r = 0; r < 4; ++r) z[n][r] = 2.f * (acc[n][r] + bv);
  }
}

__device__ __forceinline__ void store_y(const float z[4][4], short* y_s,
                                        int c0, int lr, int lg) {
  #pragma unroll
  for (int n = 0; n < 4; ++n)
    #pragma unroll
    for (int r = 0; r < 4; ++r)
      y_s[(lg * 4 + r) * 264 + c0 + n * 16 + lr] = f2bf(z[n][r]);
}

__device__ __forceinline__ void load_aF(const short* y_s, s16x8* aF, int lr, int lg) {
  #pragma unroll
  for (int kk = 0; kk < 8; ++kk)
    aF[kk] = *(const s16x8*)&y_s[lr * 264 + kk * 32 + lg * 8];
}

// ---- K0: tiled transpose+cast into the chunk-sequential layout, writing
// 8 REPLICATED copies of the weight bundle (one per XCD consumer group).
// Same-address contention fix: 2000+ waves reading one 1.2MB address set
// queue at the same L2/L3 banks; 8 copies spread the request stream.
__global__ __launch_bounds__(256) void k0_kernel(P p) {
  __shared__ float tile[64][65];
  int bx = blockIdx.x;
  const int tid = threadIdx.x;
  const float* src;
  short* dst;
  int rowoff = 0;
  if (bx < 72) {
    const int m = bx / 24; bx -= m * 24;
    src = (m == 0) ? p.Wu0 : (m == 1) ? p.Wq0 : p.Wl0;
    dst = (m == 0) ? p.wt0u : (m == 1) ? p.wt0q : p.wt0l;
  } else if (bx < 120) {
    bx -= 72; const int m = bx / 16; bx -= m * 16;
    src = (m == 0) ? p.Wu1 : (m == 1) ? p.Wq1 : p.Wl1;
    dst = (m == 0) ? p.wt1u : (m == 1) ? p.wt1q : p.wt1l;
  } else if (bx < 136) {
    bx -= 120; src = p.w1; dst = p.w1tL;
  } else {
    bx -= 136; src = p.w1; dst = p.w1tU; rowoff = 256;
  }
  const int tn = bx & 3, tk = bx >> 2;
  {
    const int r = tid >> 2, cq = (tid & 3) * 16;
    const float* s = src + (size_t)(rowoff + tk * 64 + r) * 256 + tn * 64 + cq;
    #pragma unroll
    for (int j = 0; j < 4; ++j) {
      float4 v = *(const float4*)(s + j * 4);
      tile[r][cq + j * 4 + 0] = v.x; tile[r][cq + j * 4 + 1] = v.y;
      tile[r][cq + j * 4 + 2] = v.z; tile[r][cq + j * 4 + 3] = v.w;
    }
  }
  __syncthreads();
  {
    const int nn = tid >> 2, kq = (tid & 3) * 16;
    const int n = tn * 64 + nn;
    #pragma unroll
    for (int h = 0; h < 2; ++h) {
      const int kl = kq + h * 8;
      const int kglob = tk * 64 + kl;
      const int kk = kglob >> 5, kg = (kglob & 31) >> 3;
      s16x8 v;
      #pragma unroll
      for (int ko = 0; ko < 8; ++ko) v[ko] = f2bf(tile[kl + ko][nn]);
      short* o = dst + ((size_t)(kk * 4 + kg) * 256 + n) * 8;
      #pragma unroll
      for (int cp = 0; cp < 8; ++cp)
        *(s16x8*)(o + (size_t)cp * BUNDLE) = v;
    }
  }
}

// ---- kAB: r13 structure + r19 XCD job remap + per-copy weights (bx&7).
// Job j: 0..255 u rows j*16 -> uqU ; 256..511 q -> uqQ ; 512..515 llm -> lw.
__global__ __launch_bounds__(256) void kab_kernel(P p) {
  __shared__ __align__(16) short y_s[16 * 264];
  __shared__ float ssum[4][16], ssq[4][16], mub[16], rsb[16];
  const int tid = threadIdx.x, w = tid >> 6, lane = tid & 63;
  const int lr = lane & 15, lg = lane >> 4;
  const int c0 = w * 64;
  const int bx = blockIdx.x;
  const int job = (bx < 512) ? ((bx & 7) * 64 + (bx >> 3)) : bx;
  const size_t co = (size_t)(bx & 7) * BUNDLE;  // private weight copy
  const f32x4 z4 = {0.f, 0.f, 0.f, 0.f};

  if (job < 512) {
    const bool isq = job >= 256;
    const int t = job & 255;
    const int r0 = t * 16;
    const float* arow = isq ? p.qe + (size_t)(r0 + lr) * 384
                            : p.tab + (size_t)p.uid[r0 + lr] * 384;
    const short* wt0 = (isq ? p.wt0q : p.wt0u) + co;
    const float* b0  = isq ? p.bq0 : p.bu0;
    const short* wt1 = (isq ? p.wt1q : p.wt1u) + co;
    const float* b1v = isq ? p.bq1 : p.bu1;
    short* outB      = isq ? p.uqQ : p.uqU;

    s16x8 aF[12];
    #pragma unroll
    for (int kk = 0; kk < 12; ++kk)
      aF[kk] = cvt8(*(const float4*)(arow + kk * 32 + lg * 8),
                    *(const float4*)(arow + kk * 32 + lg * 8 + 4));
    f32x4 acc[4] = {z4, z4, z4, z4};
    dgemm<12>(wt0, aF, lg, lr, c0, acc);
    float z[4][4];
    bias2(acc, b0, c0, lr, z);
    ln16(z, tid, w, lr, lg, c0, p.g0, p.be0, ssum, ssq, mub, rsb);
    store_y(z, y_s, c0, lr, lg);
    __syncthreads();
    s16x8 aH[8];
    load_aF(y_s, aH, lr, lg);
    #pragma unroll
    for (int n = 0; n < 4; ++n) acc[n] = z4;
    dgemm<8>(wt1, aH, lg, lr, c0, acc);
    bias2(acc, b1v, c0, lr, z);
    ln16(z, tid, w, lr, lg, c0, p.g1, p.be1, ssum, ssq, mub, rsb);
    store_y(z, y_s, c0, lr, lg);
    __syncthreads();
    #pragma unroll
    for (int i = 0; i < 2; ++i) {
      const int idx = i * 256 + tid;
      const int row = idx >> 5, cc = (idx & 31) * 8;
      *(s16x8*)(outB + (size_t)(r0 + row) * 256 + cc) = *(const s16x8*)&y_s[row * 264 + cc];
    }
  } else {
    const int rb = (job - 512) * 16;
    const float* arow = p.le + (size_t)(rb + lr) * 384;
    s16x8 aF[12];
    #pragma unroll
    for (int kk = 0; kk < 12; ++kk)
      aF[kk] = cvt8(*(const float4*)(arow + kk * 32 + lg * 8),
                    *(const float4*)(arow + kk * 32 + lg * 8 + 4));
    f32x4 acc[4] = {z4, z4, z4, z4};
    dgemm<12>(p.wt0l + co, aF, lg, lr, c0, acc);
    float z[4][4];
    bias2(acc, p.bl0, c0, lr, z);
    ln16(z, tid, w, lr, lg, c0, p.g0, p.be0, ssum, ssq, mub, rsb);
    store_y(z, y_s, c0, lr, lg);
    __syncthreads();
    s16x8 aH[8];
    load_aF(y_s, aH, lr, lg);
    #pragma unroll
    for (int n = 0; n < 4; ++n) acc[n] = z4;
    dgemm<8>(p.wt1l + co, aH, lg, lr, c0, acc);
    bias2(acc, p.bl1, c0, lr, z);
    ln16(z, tid, w, lr, lg, c0, p.g1, p.be1, ssum, ssq, mub, rsb);
    store_y(z, y_s, c0, lr, lg);
    __syncthreads();
    load_aF(y_s, aH, lr, lg);
    #pragma unroll
    for (int n = 0; n < 4; ++n) acc[n] = z4;
    dgemm<8>(p.w1tL + co, aH, lg, lr, c0, acc);
    #pragma unroll
    for (int n = 0; n < 4; ++n) {
      const int c = c0 + n * 16 + lr;
      const float bv = p.b1[c];
      #pragma unroll
      for (int r = 0; r < 4; ++r)
        p.lw[(size_t)(rb + lg * 4 + r) * 256 + c] = acc[n][r] + bv;
    }
  }
}

// ---- kC: GEMM2 (A = uqU+uqQ on load, per-copy w1tU) + fused score -> out ----
__global__ __launch_bounds__(256, 1) void kc_kernel(P p) {
  __shared__ __align__(16) float lw_s[64 * 256];
  __shared__ __align__(16) float uqw_s[16 * 260];
  __shared__ float w2s[256];
  const int tid = threadIdx.x, w = tid >> 6, lane = tid & 63;
  const int lr = lane & 15, lg = lane >> 4;
  const int c0 = w * 64;
  const int r0 = blockIdx.x * 16;
  const size_t co = (size_t)(blockIdx.x & 7) * BUNDLE;

  #pragma unroll
  for (int s = 0; s < 16; ++s) {
    const int i = w * 16 + s;
    gld_lds16(p.lw + (size_t)i * 256 + ((lane ^ (i & 7)) << 2),
              (char*)lw_s + (size_t)i * 1024);
  }
  __builtin_amdgcn_sched_barrier(0);
  w2s[tid] = p.w2[tid];

  s16x8 aF[8];
  {
    const s16x8* pu = (const s16x8*)(p.uqU + (size_t)(r0 + lr) * 256);
    const s16x8* pq = (const s16x8*)(p.uqQ + (size_t)(r0 + lr) * 256);
    #pragma unroll
    for (int kk = 0; kk < 8; ++kk) {
      const s16x8 a = pu[kk * 4 + lg], b = pq[kk * 4 + lg];
      s16x8 o;
      #pragma unroll
      for (int j = 0; j < 8; ++j) o[j] = f2bf(bf2f(a[j]) + bf2f(b[j]));
      aF[kk] = o;
    }
  }
  const f32x4 z4 = {0.f, 0.f, 0.f, 0.f};
  f32x4 acc[4] = {z4, z4, z4, z4};
  dgemm<8>(p.w1tU + co, aF, lg, lr, c0, acc);
  #pragma unroll
  for (int n = 0; n < 4; ++n)
    #pragma unroll
    for (int r = 0; r < 4; ++r)
      uqw_s[(lg * 4 + r) * 260 + c0 + n * 16 + lr] = acc[n][r];
  __syncthreads();  // drains vm (incl. lw_s global_load_lds) + lgkm

  const float b2v = p.b2[0];
  const int l = lane;
  float sacc[4] = {0.f, 0.f, 0.f, 0.f};
  #pragma unroll 4
  for (int jj = 0; jj < 64; ++jj) {
    const float4 lwv = *(const float4*)&lw_s[l * 256 + ((jj ^ (l & 7)) << 2)];
    const float4 w2v = *(const float4*)&w2s[jj * 4];
    #pragma unroll
    for (int bi = 0; bi < 4; ++bi) {
      const float4 uqv = *(const float4*)&uqw_s[(w * 4 + bi) * 260 + jj * 4];
      sacc[bi] += fmaxf(lwv.x + uqv.x, 0.f) * w2v.x;
      sacc[bi] += fmaxf(lwv.y + uqv.y, 0.f) * w2v.y;
      sacc[bi] += fmaxf(lwv.z + uqv.z, 0.f) * w2v.z;
      sacc[bi] += fmaxf(lwv.w + uqv.w, 0.f) * w2v.w;
    }
  }
  #pragma unroll
  for (int bi = 0; bi < 4; ++bi)
    p.out[(size_t)(r0 + w * 4 + bi) * 64 + l] = sacc[bi] + b2v;
}

extern "C" void kernel_launch(void* const* d_in, const int* in_sizes, int n_in,
                              void* d_out, int out_size, void* d_ws, size_t ws_size,
                              hipStream_t stream) {
  (void)in_sizes; (void)n_in; (void)out_size; (void)ws_size;
  P p;
  p.uid = (const int*)d_in[0];
  p.qe  = (const float*)d_in[1];
  p.le  = (const float*)d_in[2];
  p.tab = (const float*)d_in[3];
  p.Wu0 = (const float*)d_in[4];  p.bu0 = (const float*)d_in[5];
  p.Wq0 = (const float*)d_in[6];  p.bq0 = (const float*)d_in[7];
  p.Wl0 = (const float*)d_in[8];  p.bl0 = (const float*)d_in[9];
  p.g0  = (const float*)d_in[10]; p.be0 = (const float*)d_in[11];
  p.Wu1 = (const float*)d_in[12]; p.bu1 = (const float*)d_in[13];
  p.Wq1 = (const float*)d_in[14]; p.bq1 = (const float*)d_in[15];
  p.Wl1 = (const float*)d_in[16]; p.bl1 = (const float*)d_in[17];
  p.g1  = (const float*)d_in[18]; p.be1 = (const float*)d_in[19];
  p.w1  = (const float*)d_in[20]; p.b1  = (const float*)d_in[21];
  p.w2  = (const float*)d_in[22]; p.b2  = (const float*)d_in[23];

  short* wsS = (short*)d_ws;
  size_t o = 0;
  // bundle copy 0 (order defines BUNDLE offsets); copies 1..7 follow
  p.wt0u = wsS + o; o += 98304;
  p.wt0q = wsS + o; o += 98304;
  p.wt0l = wsS + o; o += 98304;
  p.wt1u = wsS + o; o += 65536;
  p.wt1q = wsS + o; o += 65536;
  p.wt1l = wsS + o; o += 65536;
  p.w1tU = wsS + o; o += 65536;
  p.w1tL = wsS + o; o += 65536;   // o == BUNDLE here
  o += BUNDLE * 7;                // copies 1..7
  p.uqU  = wsS + o; o += 1048576;
  p.uqQ  = wsS + o; o += 1048576;
  p.lw   = (float*)(wsS + o);     // 64x256 fp32 (16B-aligned byte offset)
  p.out  = (float*)d_out;

  hipLaunchKernelGGL(k0_kernel, dim3(152), dim3(256), 0, stream, p);
  hipLaunchKernelGGL(kab_kernel, dim3(516), dim3(256), 0, stream, p);
  hipLaunchKernelGGL(kc_kernel, dim3(256), dim3(256), 0, stream, p);
}

// Round 21
// 41.972 us; speedup vs baseline: 1.2065x; 1.2065x over previous
//
#include <hip/hip_runtime.h>

constexpr float EPS_LN = 1e-5f;

using f32x4 = __attribute__((ext_vector_type(4))) float;
using s16x8 = __attribute__((ext_vector_type(8))) short;

__device__ __forceinline__ short f2bf(float f) {
  union { float f; unsigned u; } v; v.f = f;
  unsigned r = v.u + 0x7fff + ((v.u >> 16) & 1);
  return (short)(r >> 16);
}
__device__ __forceinline__ float bf2f(short h) {
  union { unsigned u; float f; } v;
  v.u = ((unsigned)(unsigned short)h) << 16;
  return v.f;
}

__device__ __forceinline__ s16x8 cvt8(float4 a, float4 b) {
  s16x8 r;
  r[0] = f2bf(a.x); r[1] = f2bf(a.y); r[2] = f2bf(a.z); r[3] = f2bf(a.w);
  r[4] = f2bf(b.x); r[5] = f2bf(b.y); r[6] = f2bf(b.z); r[7] = f2bf(b.w);
  return r;
}

#define MFMA(a, b, c) __builtin_amdgcn_mfma_f32_16x16x32_bf16((a), (b), (c), 0, 0, 0)

__device__ __forceinline__ void gld_lds16(const void* g, void* l) {
  __builtin_amdgcn_global_load_lds(
      (const __attribute__((address_space(1))) unsigned int*)g,
      (__attribute__((address_space(3))) unsigned int*)l, 16, 0, 0);
}

struct P {
  const int* uid;
  const float *qe, *le, *tab;
  const float *Wu0, *bu0, *Wq0, *bq0, *Wl0, *bl0, *g0, *be0;
  const float *Wu1, *bu1, *Wq1, *bq1, *Wl1, *bl1, *g1, *be1;
  const float *w1, *b1, *w2, *b2;
  short *wt0u, *wt0q, *wt0l, *wt1u, *wt1q, *wt1l, *w1tU, *w1tL;
  short *uqU, *uqQ;
  float *lw, *out;
};

// GEMM with A streamed from LDS per K-step (ds_read_b128 just before use).
// Frees the 48 VGPRs that aF[12] used to occupy (r18: VGPR_Count=68 left
// room for only ONE B-fragment in flight -> B-loads fully serialized at
// load latency). With ~50 free regs the compiler can keep 3-4 B-groups
// in flight. a_lane = LDS base for this lane's row (+=kk*32 per step).
template<int NK>
__device__ __forceinline__ void dgemm_lds(const short* __restrict__ wt,
                                          const short* a_lane,
                                          int lg, int lr, int c0,
                                          f32x4 acc[4]) {
  #pragma unroll
  for (int kk = 0; kk < NK; ++kk) {
    const short* base = wt + (size_t)kk * 8192 + (size_t)(lg * 256 + c0 + lr) * 8;
    const s16x8 a = *(const s16x8*)(a_lane + kk * 32);  // LDS, ~60cy
    #pragma unroll
    for (int n = 0; n < 4; ++n) {
      const s16x8 bf = *(const s16x8*)(base + n * 128);
      acc[n] = MFMA(a, bf, acc[n]);
    }
  }
}

// LayerNorm over 256 cols; in-place on z[n][r] (col=c0+n*16+lr, row=lg*4+r).
__device__ __forceinline__ void ln16(float z[4][4], int tid, int w, int lr, int lg,
                                     int c0, const float* __restrict__ g,
                                     const float* __restrict__ be,
                                     float (*ssum)[16], float (*ssq)[16],
                                     float* mub, float* rsb) {
  __syncthreads();
  float s1[4] = {0, 0, 0, 0}, s2[4] = {0, 0, 0, 0};
  #pragma unroll
  for (int n = 0; n < 4; ++n)
    #pragma unroll
    for (int r = 0; r < 4; ++r) { s1[r] += z[n][r]; s2[r] += z[n][r] * z[n][r]; }
  #pragma unroll
  for (int off = 1; off < 16; off <<= 1)
    #pragma unroll
    for (int r = 0; r < 4; ++r) {
      s1[r] += __shfl_xor(s1[r], off, 64);
      s2[r] += __shfl_xor(s2[r], off, 64);
    }
  if (lr == 0) {
    #pragma unroll
    for (int r = 0; r < 4; ++r) { ssum[w][lg * 4 + r] = s1[r]; ssq[w][lg * 4 + r] = s2[r]; }
  }
  __syncthreads();
  if (tid < 16) {
    float S1 = 0, S2 = 0;
    #pragma unroll
    for (int ww = 0; ww < 4; ++ww) { S1 += ssum[ww][tid]; S2 += ssq[ww][tid]; }
    float mu = S1 * (1.f / 256.f);
    float var = S2 * (1.f / 256.f) - mu * mu;
    mub[tid] = mu;
    rsb[tid] = rsqrtf(var + EPS_LN);
  }
  __syncthreads();
  #pragma unroll
  for (int n = 0; n < 4; ++n) {
    const int c = c0 + n * 16 + lr;
    const float gv = g[c], bv = be[c];
    #pragma unroll
    for (int r = 0; r < 4; ++r) {
      const int rr = lg * 4 + r;
      z[n][r] = gv * (z[n][r] - mub[rr]) * rsb[rr] + bv;
    }
  }
}

__device__ __forceinline__ void bias2(const f32x4 acc[4], const float* __restrict__ b,
                                      int c0, int lr, float z[4][4]) {
  #pragma unroll
  for (int n = 0; n < 4; ++n) {
    const float bv = b[c0 + n * 16 + lr];
    #pragma unroll
    for (int r = 0; r < 4; ++r) z[n][r] = 2.f * (acc[n][r] + bv);
  }
}

__device__ __forceinline__ void store_y(const float z[4][4], short* y_s,
                                        int c0, int lr, int lg) {
  #pragma unroll
  for (int n = 0; n < 4; ++n)
    #pragma unroll
    for (int r = 0; r < 4; ++r)
      y_s[(lg * 4 + r) * 264 + c0 + n * 16 + lr] = f2bf(z[n][r]);
}

// Stage the 16x384 fp32 A-tile -> bf16 LDS tile a_s[16][392] (once per
// block; also removes the 4x cross-wave redundant gather of r13).
// Thread t: row t>>4, segment t&15 (24 floats).
__device__ __forceinline__ void stage_a(const float* __restrict__ base0,
                                        const int* __restrict__ uid,
                                        const float* __restrict__ tab,
                                        bool gather, int r0, int tid, short* a_s) {
  const int ar = tid >> 4, seg = tid & 15;
  const float* src = gather ? tab + (size_t)uid[r0 + ar] * 384
                            : base0 + (size_t)(r0 + ar) * 384;
  const float4* s4 = (const float4*)(src + seg * 24);
  short* o = a_s + ar * 392 + seg * 24;
  *(s16x8*)o        = cvt8(s4[0], s4[1]);
  *(s16x8*)(o + 8)  = cvt8(s4[2], s4[3]);
  *(s16x8*)(o + 16) = cvt8(s4[4], s4[5]);
}

// ---- K0: tiled transpose+cast into the CHUNK-SEQUENTIAL swizzled layout ----
__global__ __launch_bounds__(256) void k0_kernel(P p) {
  __shared__ float tile[64][65];
  int bx = blockIdx.x;
  const int tid = threadIdx.x;
  const float* src;
  short* dst;
  int rowoff = 0;
  if (bx < 72) {
    const int m = bx / 24; bx -= m * 24;
    src = (m == 0) ? p.Wu0 : (m == 1) ? p.Wq0 : p.Wl0;
    dst = (m == 0) ? p.wt0u : (m == 1) ? p.wt0q : p.wt0l;
  } else if (bx < 120) {
    bx -= 72; const int m = bx / 16; bx -= m * 16;
    src = (m == 0) ? p.Wu1 : (m == 1) ? p.Wq1 : p.Wl1;
    dst = (m == 0) ? p.wt1u : (m == 1) ? p.wt1q : p.wt1l;
  } else if (bx < 136) {
    bx -= 120; src = p.w1; dst = p.w1tL;
  } else {
    bx -= 136; src = p.w1; dst = p.w1tU; rowoff = 256;
  }
  const int tn = bx & 3, tk = bx >> 2;
  {
    const int r = tid >> 2, cq = (tid & 3) * 16;
    const float* s = src + (size_t)(rowoff + tk * 64 + r) * 256 + tn * 64 + cq;
    #pragma unroll
    for (int j = 0; j < 4; ++j) {
      float4 v = *(const float4*)(s + j * 4);
      tile[r][cq + j * 4 + 0] = v.x; tile[r][cq + j * 4 + 1] = v.y;
      tile[r][cq + j * 4 + 2] = v.z; tile[r][cq + j * 4 + 3] = v.w;
    }
  }
  __syncthreads();
  {
    const int nn = tid >> 2, kq = (tid & 3) * 16;
    const int n = tn * 64 + nn;
    #pragma unroll
    for (int h = 0; h < 2; ++h) {
      const int kl = kq + h * 8;
      const int kglob = tk * 64 + kl;
      const int kk = kglob >> 5, kg = (kglob & 31) >> 3;
      s16x8 v;
      #pragma unroll
      for (int ko = 0; ko < 8; ++ko) v[ko] = f2bf(tile[kl + ko][nn]);
      *(s16x8*)(dst + ((size_t)(kk * 4 + kg) * 256 + n) * 8) = v;
    }
  }
}

// ---- kAB: r13 structure with A streamed from LDS (frees 48 VGPR for
// B-load pipelining). bx 0..255: u -> uqU ; 256..511: q -> uqQ ;
// 512..515: llm -> lw.
__global__ __launch_bounds__(256) void kab_kernel(P p) {
  __shared__ __align__(16) short a_s[16 * 392];
  __shared__ __align__(16) short y_s[16 * 264];
  __shared__ float ssum[4][16], ssq[4][16], mub[16], rsb[16];
  const int tid = threadIdx.x, w = tid >> 6, lane = tid & 63;
  const int lr = lane & 15, lg = lane >> 4;
  const int c0 = w * 64;
  const int bx = blockIdx.x;
  const f32x4 z4 = {0.f, 0.f, 0.f, 0.f};
  const short* aL0 = a_s + lr * 392 + lg * 8;  // layer-0 A lane base
  const short* aL1 = y_s + lr * 264 + lg * 8;  // layer-1 A lane base

  if (bx < 512) {
    const bool isq = bx >= 256;
    const int t = bx & 255;
    const int r0 = t * 16;
    const short* wt0 = isq ? p.wt0q : p.wt0u;
    const float* b0  = isq ? p.bq0 : p.bu0;
    const short* wt1 = isq ? p.wt1q : p.wt1u;
    const float* b1v = isq ? p.bq1 : p.bu1;
    short* outB      = isq ? p.uqQ : p.uqU;

    stage_a(p.qe, p.uid, p.tab, !isq, r0, tid, a_s);
    __syncthreads();
    f32x4 acc[4] = {z4, z4, z4, z4};
    dgemm_lds<12>(wt0, aL0, lg, lr, c0, acc);
    float z[4][4];
    bias2(acc, b0, c0, lr, z);
    ln16(z, tid, w, lr, lg, c0, p.g0, p.be0, ssum, ssq, mub, rsb);
    store_y(z, y_s, c0, lr, lg);
    __syncthreads();
    #pragma unroll
    for (int n = 0; n < 4; ++n) acc[n] = z4;
    dgemm_lds<8>(wt1, aL1, lg, lr, c0, acc);
    bias2(acc, b1v, c0, lr, z);
    ln16(z, tid, w, lr, lg, c0, p.g1, p.be1, ssum, ssq, mub, rsb);
    store_y(z, y_s, c0, lr, lg);
    __syncthreads();
    #pragma unroll
    for (int i = 0; i < 2; ++i) {
      const int idx = i * 256 + tid;
      const int row = idx >> 5, cc = (idx & 31) * 8;
      *(s16x8*)(outB + (size_t)(r0 + row) * 256 + cc) = *(const s16x8*)&y_s[row * 264 + cc];
    }
  } else {
    const int rb = (bx - 512) * 16;
    stage_a(p.le, p.uid, p.tab, false, rb, tid, a_s);
    __syncthreads();
    f32x4 acc[4] = {z4, z4, z4, z4};
    dgemm_lds<12>(p.wt0l, aL0, lg, lr, c0, acc);
    float z[4][4];
    bias2(acc, p.bl0, c0, lr, z);
    ln16(z, tid, w, lr, lg, c0, p.g0, p.be0, ssum, ssq, mub, rsb);
    store_y(z, y_s, c0, lr, lg);
    __syncthreads();
    #pragma unroll
    for (int n = 0; n < 4; ++n) acc[n] = z4;
    dgemm_lds<8>(p.wt1l, aL1, lg, lr, c0, acc);
    bias2(acc, p.bl1, c0, lr, z);
    ln16(z, tid, w, lr, lg, c0, p.g1, p.be1, ssum, ssq, mub, rsb);
    store_y(z, y_s, c0, lr, lg);
    __syncthreads();
    #pragma unroll
    for (int n = 0; n < 4; ++n) acc[n] = z4;
    dgemm_lds<8>(p.w1tL, aL1, lg, lr, c0, acc);
    #pragma unroll
    for (int n = 0; n < 4; ++n) {
      const int c = c0 + n * 16 + lr;
      const float bv = p.b1[c];
      #pragma unroll
      for (int r = 0; r < 4; ++r)
        p.lw[(size_t)(rb + lg * 4 + r) * 256 + c] = acc[n][r] + bv;
    }
  }
}

// ---- kC: GEMM2 (A = uqU+uqQ on load) + fused score -> out ----
__global__ __launch_bounds__(256, 1) void kc_kernel(P p) {
  __shared__ __align__(16) float lw_s[64 * 256];
  __shared__ __align__(16) float uqw_s[16 * 260];
  __shared__ float w2s[256];
  const int tid = threadIdx.x, w = tid >> 6, lane = tid & 63;
  const int lr = lane & 15, lg = lane >> 4;
  const int c0 = w * 64;
  const int r0 = blockIdx.x * 16;

  #pragma unroll
  for (int s = 0; s < 16; ++s) {
    const int i = w * 16 + s;
    gld_lds16(p.lw + (size_t)i * 256 + ((lane ^ (i & 7)) << 2),
              (char*)lw_s + (size_t)i * 1024);
  }
  __builtin_amdgcn_sched_barrier(0);
  w2s[tid] = p.w2[tid];

  s16x8 aF[8];
  {
    const s16x8* pu = (const s16x8*)(p.uqU + (size_t)(r0 + lr) * 256);
    const s16x8* pq = (const s16x8*)(p.uqQ + (size_t)(r0 + lr) * 256);
    #pragma unroll
    for (int kk = 0; kk < 8; ++kk) {
      const s16x8 a = pu[kk * 4 + lg], b = pq[kk * 4 + lg];
      s16x8 o;
      #pragma unroll
      for (int j = 0; j < 8; ++j) o[j] = f2bf(bf2f(a[j]) + bf2f(b[j]));
      aF[kk] = o;
    }
  }
  const f32x4 z4 = {0.f, 0.f, 0.f, 0.f};
  f32x4 acc[4] = {z4, z4, z4, z4};
  #pragma unroll
  for (int kk = 0; kk < 8; ++kk) {
    const short* base = p.w1tU + (size_t)kk * 8192 + (size_t)(lg * 256 + c0 + lr) * 8;
    #pragma unroll
    for (int n = 0; n < 4; ++n)
      acc[n] = MFMA(aF[kk], *(const s16x8*)(base + n * 128), acc[n]);
  }
  #pragma unroll
  for (int n = 0; n < 4; ++n)
    #pragma unroll
    for (int r = 0; r < 4; ++r)
      uqw_s[(lg * 4 + r) * 260 + c0 + n * 16 + lr] = acc[n][r];
  __syncthreads();  // drains vm (incl. lw_s global_load_lds) + lgkm

  const float b2v = p.b2[0];
  const int l = lane;
  float sacc[4] = {0.f, 0.f, 0.f, 0.f};
  #pragma unroll 4
  for (int jj = 0; jj < 64; ++jj) {
    const float4 lwv = *(const float4*)&lw_s[l * 256 + ((jj ^ (l & 7)) << 2)];
    const float4 w2v = *(const float4*)&w2s[jj * 4];
    #pragma unroll
    for (int bi = 0; bi < 4; ++bi) {
      const float4 uqv = *(const float4*)&uqw_s[(w * 4 + bi) * 260 + jj * 4];
      sacc[bi] += fmaxf(lwv.x + uqv.x, 0.f) * w2v.x;
      sacc[bi] += fmaxf(lwv.y + uqv.y, 0.f) * w2v.y;
      sacc[bi] += fmaxf(lwv.z + uqv.z, 0.f) * w2v.z;
      sacc[bi] += fmaxf(lwv.w + uqv.w, 0.f) * w2v.w;
    }
  }
  #pragma unroll
  for (int bi = 0; bi < 4; ++bi)
    p.out[(size_t)(r0 + w * 4 + bi) * 64 + l] = sacc[bi] + b2v;
}

extern "C" void kernel_launch(void* const* d_in, const int* in_sizes, int n_in,
                              void* d_out, int out_size, void* d_ws, size_t ws_size,
                              hipStream_t stream) {
  (void)in_sizes; (void)n_in; (void)out_size; (void)ws_size;
  P p;
  p.uid = (const int*)d_in[0];
  p.qe  = (const float*)d_in[1];
  p.le  = (const float*)d_in[2];
  p.tab = (const float*)d_in[3];
  p.Wu0 = (const float*)d_in[4];  p.bu0 = (const float*)d_in[5];
  p.Wq0 = (const float*)d_in[6];  p.bq0 = (const float*)d_in[7];
  p.Wl0 = (const float*)d_in[8];  p.bl0 = (const float*)d_in[9];
  p.g0  = (const float*)d_in[10]; p.be0 = (const float*)d_in[11];
  p.Wu1 = (const float*)d_in[12]; p.bu1 = (const float*)d_in[13];
  p.Wq1 = (const float*)d_in[14]; p.bq1 = (const float*)d_in[15];
  p.Wl1 = (const float*)d_in[16]; p.bl1 = (const float*)d_in[17];
  p.g1  = (const float*)d_in[18]; p.be1 = (const float*)d_in[19];
  p.w1  = (const float*)d_in[20]; p.b1  = (const float*)d_in[21];
  p.w2  = (const float*)d_in[22]; p.b2  = (const float*)d_in[23];

  short* wsS = (short*)d_ws;
  size_t o = 0;
  p.wt0u = wsS + o; o += 98304;    // 12 chunks x 8192 shorts (K=384)
  p.wt0q = wsS + o; o += 98304;
  p.wt0l = wsS + o; o += 98304;
  p.wt1u = wsS + o; o += 65536;    // 8 chunks x 8192 (K=256)
  p.wt1q = wsS + o; o += 65536;
  p.wt1l = wsS + o; o += 65536;
  p.w1tU = wsS + o; o += 65536;    // w1[256:512] swizzled
  p.w1tL = wsS + o; o += 65536;    // w1[0:256] swizzled
  p.uqU  = wsS + o; o += 1048576;  // 4096x256 bf16 normalized u1
  p.uqQ  = wsS + o; o += 1048576;  // 4096x256 bf16 normalized q1
  p.lw   = (float*)(wsS + o);      // 64x256 fp32 (16B-aligned byte offset)
  p.out  = (float*)d_out;

  hipLaunchKernelGGL(k0_kernel, dim3(152), dim3(256), 0, stream, p);
  hipLaunchKernelGGL(kab_kernel, dim3(516), dim3(256), 0, stream, p);
  hipLaunchKernelGGL(kc_kernel, dim3(256), dim3(256), 0, stream, p);
}